// Round 5
// baseline (1255.375 us; speedup 1.0000x reference)
//
#include <hip/hip_runtime.h>
#include <hip/hip_fp16.h>

typedef _Float16 half8v __attribute__((ext_vector_type(8)));
typedef _Float16 half2v __attribute__((ext_vector_type(2)));
typedef float f32x4 __attribute__((ext_vector_type(4)));

// DPP butterfly-add within 16-lane rows (pure VALU, no LDS traffic).
#define DPP_XADD(x, ctrl)                                                          \
  x += __builtin_bit_cast(float, __builtin_amdgcn_mov_dpp(                         \
           __builtin_bit_cast(int, x), ctrl, 0xf, 0xf, true))

// ---------------- prep kernel (1 block, runs once per launch) ----------------
// ws layout: [0,8192)      W frags : half wf[ks(2)][nt(4)][lane(64)][j(8)]
//            [8192,10240)  pvec frags: half pf[ks(2)][lane(64)][j(8)] (col 0 only)
//            [10240,13376) pair table: uint tbl[784] = (ri*72)<<16 | (ci*72)
__global__ void afm_prep(const float* __restrict__ W, const float* __restrict__ pvec,
                         unsigned char* __restrict__ ws) {
  const int tid = threadIdx.x;
  _Float16* wf = (_Float16*)ws;
  _Float16* pf = (_Float16*)(ws + 8192);
  unsigned int* tbl = (unsigned int*)(ws + 10240);
  for (int idx = tid; idx < 4096; idx += 256) {
    int j = idx & 7, lane = (idx >> 3) & 63, nt = (idx >> 9) & 3, ks = idx >> 11;
    int k = ks * 32 + (lane >> 4) * 8 + j;   // e index
    int u = nt * 16 + (lane & 15);           // u index
    wf[idx] = (_Float16)W[k * 64 + u];
  }
  for (int idx = tid; idx < 1024; idx += 256) {
    int j = idx & 7, lane = (idx >> 3) & 63, ks = idx >> 9;
    int k = ks * 32 + (lane >> 4) * 8 + j;
    pf[idx] = ((lane & 15) == 0) ? (_Float16)pvec[k] : (_Float16)0.f;
  }
  for (int p = tid; p < 784; p += 256) {
    int pc = p > 779 ? 779 : p;
    int i = 0, rem = pc;
    while (rem >= 39 - i) { rem -= 39 - i; ++i; }
    int j = i + 1 + rem;
    tbl[p] = ((unsigned)(i * 72) << 16) | (unsigned)(j * 72);
  }
}

#define ISSUE_READS(slot, offw)                                                    \
  do {                                                                             \
    const _Float16* xi_ = &xh[((offw) >> 16) + eoff];                              \
    const _Float16* xj_ = &xh[((offw) & 0xffffu) + eoff];                          \
    xia[slot][0] = *(const half8v*)xi_;                                            \
    xia[slot][1] = *(const half8v*)(xi_ + 32);                                     \
    xja[slot][0] = *(const half8v*)xj_;                                            \
    xja[slot][1] = *(const half8v*)(xj_ + 32);                                     \
  } while (0)

// ---------------- main kernel: one 8-wave block per batch row ----------------
__global__ __launch_bounds__(512) void afm_main(
    const float* __restrict__ x, const float* __restrict__ bvec,
    const float* __restrict__ hvec, const unsigned char* __restrict__ ws,
    float* __restrict__ out) {
  // LDS: 5760 + 3136 + 3136 + 96 = 12.1 KB
  __shared__ __align__(16) _Float16 xh[40 * 72];  // row stride 144 B
  __shared__ float scs[784];
  __shared__ float s2s[784];
  __shared__ float red[24];

  const int tid = threadIdx.x;
  const int b = blockIdx.x;
  const int lane = tid & 63;
  const int wid = tid >> 6;      // 0..7
  const int m = lane & 15, kg = lane >> 4;

  // ---- issue x[b] loads (HBM, longest latency) ----
  const float4* xg = (const float4*)(x + b * 2560);
  float4 v0 = xg[tid];
  float4 v1;
  if (tid < 128) v1 = xg[512 + tid];

  // ---- issue table + fragment + bias/h loads (L1/L2-hot after first blocks) ----
  const unsigned int* tbl_g = (const unsigned int*)(ws + 10240);
  unsigned int off[7];
#pragma unroll
  for (int i = 0; i < 7; ++i) {
    int tt = wid + 8 * i;
    tt = tt > 48 ? 48 : tt;
    off[i] = tbl_g[16 * tt + m];
  }
  const half8v* wfg = (const half8v*)ws;
  half8v wf[2][4];
#pragma unroll
  for (int ks = 0; ks < 2; ++ks)
#pragma unroll
    for (int nt = 0; nt < 4; ++nt) wf[ks][nt] = wfg[(ks * 4 + nt) * 64 + lane];
  const half8v* pfg = (const half8v*)(ws + 8192);
  half8v pf[2] = {pfg[lane], pfg[64 + lane]};
  float bu[4], hu[4];
#pragma unroll
  for (int nt = 0; nt < 4; ++nt) {
    int uu = nt * 16 + m;
    bu[nt] = bvec[uu];
    hu[nt] = hvec[uu];
  }

  // ---- stage x -> LDS fp16 (row stride 72 halves) ----
  {
    int f = tid >> 4, e4 = tid & 15;
    half2v* dst = (half2v*)&xh[f * 72 + e4 * 4];
    dst[0] = __builtin_bit_cast(half2v, __builtin_amdgcn_cvt_pkrtz(v0.x, v0.y));
    dst[1] = __builtin_bit_cast(half2v, __builtin_amdgcn_cvt_pkrtz(v0.z, v0.w));
  }
  if (tid < 128) {
    int g = 512 + tid;
    int f = g >> 4, e4 = g & 15;
    half2v* dst = (half2v*)&xh[f * 72 + e4 * 4];
    dst[0] = __builtin_bit_cast(half2v, __builtin_amdgcn_cvt_pkrtz(v1.x, v1.y));
    dst[1] = __builtin_bit_cast(half2v, __builtin_amdgcn_cvt_pkrtz(v1.z, v1.w));
  }
  __syncthreads();

  // ---- phase A: 6-7 tiles/wave, 2-deep software pipeline ----
  const int eoff = kg * 8;
  const int NT = (48 - wid) / 8 + 1;  // wave 0: 7, waves 1-7: 6
  half8v xia[2][2], xja[2][2];
  ISSUE_READS(0, off[0]);
#pragma unroll 7
  for (int i = 0; i < 7; ++i) {
    if (i >= NT) break;
    const int cur = i & 1;
    if (i + 1 < NT) ISSUE_READS(cur ^ 1, off[i + 1]);
    half8v a0 = xia[cur][0] * xja[cur][0];   // ip, e = kg*8+j
    half8v a1 = xia[cur][1] * xja[cur][1];   // ip, e = 32+kg*8+j
    f32x4 acc[4];
#pragma unroll
    for (int nt = 0; nt < 4; ++nt) {
      acc[nt] = (f32x4){bu[nt], bu[nt], bu[nt], bu[nt]};
      acc[nt] = __builtin_amdgcn_mfma_f32_16x16x32_f16(a0, wf[0][nt], acc[nt], 0, 0, 0);
      acc[nt] = __builtin_amdgcn_mfma_f32_16x16x32_f16(a1, wf[1][nt], acc[nt], 0, 0, 0);
    }
    f32x4 accp = (f32x4){0.f, 0.f, 0.f, 0.f};
    accp = __builtin_amdgcn_mfma_f32_16x16x32_f16(a0, pf[0], accp, 0, 0, 0);
    accp = __builtin_amdgcn_mfma_f32_16x16x32_f16(a1, pf[1], accp, 0, 0, 0);

    const int t16 = 16 * (wid + 8 * i);
#pragma unroll
    for (int r = 0; r < 4; ++r) {
      float s = fmaxf(acc[0][r], 0.f) * hu[0] + fmaxf(acc[1][r], 0.f) * hu[1] +
                fmaxf(acc[2][r], 0.f) * hu[2] + fmaxf(acc[3][r], 0.f) * hu[3];
      DPP_XADD(s, 0xB1);   // xor 1
      DPP_XADD(s, 0x4E);   // xor 2
      DPP_XADD(s, 0x141);  // row half mirror (xor 4 within 8)
      DPP_XADD(s, 0x140);  // row mirror (xor 8 within 16)
      int pr = t16 + kg * 4 + r;
      if (m == 0 && pr < 780) {
        scs[pr] = s;
        s2s[pr] = accp[r];  // col 0 of pvec-MFMA = ip . pvec
      }
    }
  }
  __syncthreads();

  // ---- phase B: softmax over 780 + weighted sum of s2 (512 threads) ----
  const int p1 = tid + 512;
  float sv0 = scs[tid];
  float sv1 = (p1 < 780) ? scs[p1] : -1e30f;
  float mx = fmaxf(sv0, sv1);
#pragma unroll
  for (int o = 32; o; o >>= 1) mx = fmaxf(mx, __shfl_xor(mx, o));
  if (lane == 0) red[wid] = mx;
  __syncthreads();
  mx = red[0];
#pragma unroll
  for (int w = 1; w < 8; ++w) mx = fmaxf(mx, red[w]);
  float e0 = __expf(sv0 - mx);
  float num = e0 * s2s[tid];
  float den = e0;
  if (p1 < 780) {
    float e1 = __expf(sv1 - mx);
    num += e1 * s2s[p1];
    den += e1;
  }
#pragma unroll
  for (int o = 32; o; o >>= 1) {
    num += __shfl_xor(num, o);
    den += __shfl_xor(den, o);
  }
  if (lane == 0) { red[8 + wid] = num; red[16 + wid] = den; }
  __syncthreads();
  if (tid == 0) {
    float ns = 0.f, ds = 0.f;
#pragma unroll
    for (int w = 0; w < 8; ++w) { ns += red[8 + w]; ds += red[16 + w]; }
    out[b] = ns / ds;
  }
}

extern "C" void kernel_launch(void* const* d_in, const int* in_sizes, int n_in,
                              void* d_out, int out_size, void* d_ws, size_t ws_size,
                              hipStream_t stream) {
  const float* x    = (const float*)d_in[0];  // [4096,40,64]
  const float* W    = (const float*)d_in[1];  // [64,64]
  const float* bvec = (const float*)d_in[2];  // [64]
  const float* hvec = (const float*)d_in[3];  // [64,1]
  const float* pvec = (const float*)d_in[4];  // [64,1]
  float* out = (float*)d_out;                 // [4096,1]
  unsigned char* ws = (unsigned char*)d_ws;   // needs 13.4 KB

  hipLaunchKernelGGL(afm_prep, dim3(1), dim3(256), 0, stream, W, pvec, ws);
  hipLaunchKernelGGL(afm_main, dim3(4096), dim3(512), 0, stream,
                     x, bvec, hvec, ws, out);
}

// Round 6
// 136.875 us; speedup vs baseline: 9.1717x; 9.1717x over previous
//
#include <hip/hip_runtime.h>
#include <hip/hip_fp16.h>

typedef _Float16 half8v __attribute__((ext_vector_type(8)));
typedef _Float16 half2v __attribute__((ext_vector_type(2)));
typedef float f32x4 __attribute__((ext_vector_type(4)));

// DPP butterfly-add within 16-lane rows (pure VALU, no LDS traffic).
#define DPP_XADD(x, ctrl)                                                          \
  x += __builtin_bit_cast(float, __builtin_amdgcn_mov_dpp(                         \
           __builtin_bit_cast(int, x), ctrl, 0xf, 0xf, true))

// ---------------- prep kernel (1 block, runs once per launch) ----------------
// ws layout: [0,8192)      W frags : half wf[ks(2)][nt(4)][lane(64)][j(8)]
//            [8192,10240)  pvec frags: half pf[ks(2)][lane(64)][j(8)] (col 0 only)
//            [10240,13376) pair table: uint tbl[784] = (ri*72)<<16 | (ci*72)
__global__ void afm_prep(const float* __restrict__ W, const float* __restrict__ pvec,
                         unsigned char* __restrict__ ws) {
  const int tid = threadIdx.x;
  _Float16* wf = (_Float16*)ws;
  _Float16* pf = (_Float16*)(ws + 8192);
  unsigned int* tbl = (unsigned int*)(ws + 10240);
  for (int idx = tid; idx < 4096; idx += 256) {
    int j = idx & 7, lane = (idx >> 3) & 63, nt = (idx >> 9) & 3, ks = idx >> 11;
    int k = ks * 32 + (lane >> 4) * 8 + j;   // e index
    int u = nt * 16 + (lane & 15);           // u index
    wf[idx] = (_Float16)W[k * 64 + u];
  }
  for (int idx = tid; idx < 1024; idx += 256) {
    int j = idx & 7, lane = (idx >> 3) & 63, ks = idx >> 9;
    int k = ks * 32 + (lane >> 4) * 8 + j;
    pf[idx] = ((lane & 15) == 0) ? (_Float16)pvec[k] : (_Float16)0.f;
  }
  for (int p = tid; p < 784; p += 256) {
    int pc = p > 779 ? 779 : p;
    int i = 0, rem = pc;
    while (rem >= 39 - i) { rem -= 39 - i; ++i; }
    int j = i + 1 + rem;
    tbl[p] = ((unsigned)(i * 72) << 16) | (unsigned)(j * 72);
  }
}

#define ISSUE_READS(slot, offw)                                                    \
  do {                                                                             \
    const _Float16* xi_ = &xh[((offw) >> 16) + eoff];                              \
    const _Float16* xj_ = &xh[((offw) & 0xffffu) + eoff];                          \
    xia[slot][0] = *(const half8v*)xi_;                                            \
    xia[slot][1] = *(const half8v*)(xi_ + 32);                                     \
    xja[slot][0] = *(const half8v*)xj_;                                            \
    xja[slot][1] = *(const half8v*)(xj_ + 32);                                     \
  } while (0)

// ---------------- main kernel: one 4-wave block per batch row ----------------
// NOTE: phase-A loop MUST have a compile-time trip count (13) and no break —
// a data-dependent break rolls the loop and sends xia/xja/off to scratch
// (rule #20), which cost 20x in R5.
__global__ __launch_bounds__(256) void afm_main(
    const float* __restrict__ x, const float* __restrict__ bvec,
    const float* __restrict__ hvec, const unsigned char* __restrict__ ws,
    float* __restrict__ out) {
  // LDS: 5760 + 3136 + 3136 + 48 = 12.1 KB
  __shared__ __align__(16) _Float16 xh[40 * 72];  // row stride 144 B
  __shared__ float scs[784];
  __shared__ float s2s[784];
  __shared__ float red[12];

  const int tid = threadIdx.x;
  const int b = blockIdx.x;
  const int lane = tid & 63;
  const int wid = tid >> 6;      // 0..3
  const int m = lane & 15, kg = lane >> 4;

  // ---- issue x[b] loads first (longest latency path) ----
  const float4* xg = (const float4*)(x + b * 2560);
  float4 v0 = xg[tid];
  float4 v1 = xg[256 + tid];
  float4 v2;
  if (tid < 128) v2 = xg[512 + tid];

  // ---- all 13 pair-table offsets up-front, static indices (registers) ----
  const unsigned int* tbl_g = (const unsigned int*)(ws + 10240);
  unsigned int off[13];
#pragma unroll
  for (int i = 0; i < 13; ++i) {
    int tt = wid + 4 * i;
    tt = tt > 48 ? 48 : tt;       // waves 1-3 redo tile 48 (identical writes)
    off[i] = tbl_g[16 * tt + m];
  }

  // ---- W/pvec fragments + bias/h (L2-hot) ----
  const half8v* wfg = (const half8v*)ws;
  half8v wf[2][4];
#pragma unroll
  for (int ks = 0; ks < 2; ++ks)
#pragma unroll
    for (int nt = 0; nt < 4; ++nt) wf[ks][nt] = wfg[(ks * 4 + nt) * 64 + lane];
  const half8v* pfg = (const half8v*)(ws + 8192);
  half8v pf[2] = {pfg[lane], pfg[64 + lane]};
  float bu[4], hu[4];
#pragma unroll
  for (int nt = 0; nt < 4; ++nt) {
    int uu = nt * 16 + m;
    bu[nt] = bvec[uu];
    hu[nt] = hvec[uu];
  }

  // ---- stage x -> LDS fp16 (row stride 72 halves) ----
  {
    int f = tid >> 4, e4 = tid & 15;
    half2v* dst = (half2v*)&xh[f * 72 + e4 * 4];
    dst[0] = __builtin_bit_cast(half2v, __builtin_amdgcn_cvt_pkrtz(v0.x, v0.y));
    dst[1] = __builtin_bit_cast(half2v, __builtin_amdgcn_cvt_pkrtz(v0.z, v0.w));
  }
  {
    int g = 256 + tid;
    int f = g >> 4, e4 = g & 15;
    half2v* dst = (half2v*)&xh[f * 72 + e4 * 4];
    dst[0] = __builtin_bit_cast(half2v, __builtin_amdgcn_cvt_pkrtz(v1.x, v1.y));
    dst[1] = __builtin_bit_cast(half2v, __builtin_amdgcn_cvt_pkrtz(v1.z, v1.w));
  }
  if (tid < 128) {
    int g = 512 + tid;
    int f = g >> 4, e4 = g & 15;
    half2v* dst = (half2v*)&xh[f * 72 + e4 * 4];
    dst[0] = __builtin_bit_cast(half2v, __builtin_amdgcn_cvt_pkrtz(v2.x, v2.y));
    dst[1] = __builtin_bit_cast(half2v, __builtin_amdgcn_cvt_pkrtz(v2.z, v2.w));
  }
  __syncthreads();

  // ---- phase A: 13 tiles/wave, 2-deep software pipeline, fully unrolled ----
  const int eoff = kg * 8;
  half8v xia[2][2], xja[2][2];
  ISSUE_READS(0, off[0]);
#pragma unroll
  for (int i = 0; i < 13; ++i) {
    const int cur = i & 1;
    if (i < 12) ISSUE_READS(cur ^ 1, off[i + 1]);
    half8v a0 = xia[cur][0] * xja[cur][0];   // ip, e = kg*8+j
    half8v a1 = xia[cur][1] * xja[cur][1];   // ip, e = 32+kg*8+j
    f32x4 acc[4];
#pragma unroll
    for (int nt = 0; nt < 4; ++nt) {
      acc[nt] = (f32x4){bu[nt], bu[nt], bu[nt], bu[nt]};
      acc[nt] = __builtin_amdgcn_mfma_f32_16x16x32_f16(a0, wf[0][nt], acc[nt], 0, 0, 0);
      acc[nt] = __builtin_amdgcn_mfma_f32_16x16x32_f16(a1, wf[1][nt], acc[nt], 0, 0, 0);
    }
    f32x4 accp = (f32x4){0.f, 0.f, 0.f, 0.f};
    accp = __builtin_amdgcn_mfma_f32_16x16x32_f16(a0, pf[0], accp, 0, 0, 0);
    accp = __builtin_amdgcn_mfma_f32_16x16x32_f16(a1, pf[1], accp, 0, 0, 0);

    int tt = wid + 4 * i;
    tt = tt > 48 ? 48 : tt;
    const int t16 = 16 * tt;
#pragma unroll
    for (int r = 0; r < 4; ++r) {
      float s = fmaxf(acc[0][r], 0.f) * hu[0] + fmaxf(acc[1][r], 0.f) * hu[1] +
                fmaxf(acc[2][r], 0.f) * hu[2] + fmaxf(acc[3][r], 0.f) * hu[3];
      DPP_XADD(s, 0xB1);   // xor 1
      DPP_XADD(s, 0x4E);   // xor 2
      DPP_XADD(s, 0x141);  // row half mirror (xor 4 within 8)
      DPP_XADD(s, 0x140);  // row mirror (xor 8 within 16)
      int pr = t16 + kg * 4 + r;
      if (m == 0 && pr < 780) {
        scs[pr] = s;
        s2s[pr] = accp[r];  // col 0 of pvec-MFMA = ip . pvec
      }
    }
  }
  __syncthreads();

  // ---- phase B: softmax over 780 + weighted sum of s2 (256 threads) ----
  float sv[4];
  float mx = -1e30f;
#pragma unroll
  for (int k2 = 0; k2 < 4; ++k2) {
    int p = tid + k2 * 256;
    if (p < 780) {
      sv[k2] = scs[p];
      mx = fmaxf(mx, sv[k2]);
    } else {
      sv[k2] = -1e30f;
    }
  }
#pragma unroll
  for (int o = 32; o; o >>= 1) mx = fmaxf(mx, __shfl_xor(mx, o));
  if (lane == 0) red[wid] = mx;
  __syncthreads();
  mx = fmaxf(fmaxf(red[0], red[1]), fmaxf(red[2], red[3]));
  float num = 0.f, den = 0.f;
#pragma unroll
  for (int k2 = 0; k2 < 4; ++k2) {
    int p = tid + k2 * 256;
    if (p < 780) {
      float e = __expf(sv[k2] - mx);
      num += e * s2s[p];
      den += e;
    }
  }
#pragma unroll
  for (int o = 32; o; o >>= 1) {
    num += __shfl_xor(num, o);
    den += __shfl_xor(den, o);
  }
  if (lane == 0) { red[4 + wid] = num; red[8 + wid] = den; }
  __syncthreads();
  if (tid == 0)
    out[b] = (red[4] + red[5] + red[6] + red[7]) /
             (red[8] + red[9] + red[10] + red[11]);
}

extern "C" void kernel_launch(void* const* d_in, const int* in_sizes, int n_in,
                              void* d_out, int out_size, void* d_ws, size_t ws_size,
                              hipStream_t stream) {
  const float* x    = (const float*)d_in[0];  // [4096,40,64]
  const float* W    = (const float*)d_in[1];  // [64,64]
  const float* bvec = (const float*)d_in[2];  // [64]
  const float* hvec = (const float*)d_in[3];  // [64,1]
  const float* pvec = (const float*)d_in[4];  // [64,1]
  float* out = (float*)d_out;                 // [4096,1]
  unsigned char* ws = (unsigned char*)d_ws;   // needs 13.4 KB

  hipLaunchKernelGGL(afm_prep, dim3(1), dim3(256), 0, stream, W, pvec, ws);
  hipLaunchKernelGGL(afm_main, dim3(4096), dim3(256), 0, stream,
                     x, bvec, hvec, ws, out);
}

// Round 8
// 129.720 us; speedup vs baseline: 9.6776x; 1.0552x over previous
//
#include <hip/hip_runtime.h>
#include <hip/hip_fp16.h>

typedef _Float16 half8v __attribute__((ext_vector_type(8)));
typedef _Float16 half2v __attribute__((ext_vector_type(2)));
typedef float f32x4 __attribute__((ext_vector_type(4)));

// ---------------- prep kernel (1 block, runs once per launch) ----------------
// ws layout: [0,8192)      W frags : half wf[ks(2)][nt(4)][lane(64)][j(8)]
//            [8192,10240)  pvec frags: half pf[ks(2)][lane(64)][j(8)] (row 0 only)
//            [10240,13376) pair table: uint tbl[784] = (ri*72)<<16 | (ci*72)
__global__ void afm_prep(const float* __restrict__ W, const float* __restrict__ pvec,
                         unsigned char* __restrict__ ws) {
  const int tid = threadIdx.x;
  _Float16* wf = (_Float16*)ws;
  _Float16* pf = (_Float16*)(ws + 8192);
  unsigned int* tbl = (unsigned int*)(ws + 10240);
  for (int idx = tid; idx < 4096; idx += 256) {
    int j = idx & 7, lane = (idx >> 3) & 63, nt = (idx >> 9) & 3, ks = idx >> 11;
    int k = ks * 32 + (lane >> 4) * 8 + j;   // e index
    int u = nt * 16 + (lane & 15);           // u index
    wf[idx] = (_Float16)W[k * 64 + u];
  }
  for (int idx = tid; idx < 1024; idx += 256) {
    int j = idx & 7, lane = (idx >> 3) & 63, ks = idx >> 9;
    int k = ks * 32 + (lane >> 4) * 8 + j;
    pf[idx] = ((lane & 15) == 0) ? (_Float16)pvec[k] : (_Float16)0.f;
  }
  for (int p = tid; p < 784; p += 256) {
    int pc = p > 779 ? 779 : p;
    int i = 0, rem = pc;
    while (rem >= 39 - i) { rem -= 39 - i; ++i; }
    int j = i + 1 + rem;
    tbl[p] = ((unsigned)(i * 72) << 16) | (unsigned)(j * 72);
  }
}

#define ISSUE_READS(slot, offw)                                                    \
  do {                                                                             \
    const _Float16* xi_ = &xh[((offw) >> 16) + eoff];                              \
    const _Float16* xj_ = &xh[((offw) & 0xffffu) + eoff];                          \
    xia[slot][0] = *(const half8v*)xi_;                                            \
    xia[slot][1] = *(const half8v*)(xi_ + 32);                                     \
    xja[slot][0] = *(const half8v*)xj_;                                            \
    xja[slot][1] = *(const half8v*)(xj_ + 32);                                     \
  } while (0)

// ---------------- main kernel: one 4-wave block per batch row ----------------
// Transposed-V design: D[u][pair] = mfma(W^T-frag, ip^T-frag) so that
//   - bias feeds the MFMA C operand directly (no acc-init movs),
//   - score dot over u is lane-local (16 max + 16 fma) + 2 shuffles,
//   - scs/s2s writes are 16-lane coalesced.
// Phase-A loop MUST stay compile-time-unrolled, no data-dependent break
// (rule #20 — cost 20x in R5).
// R7 bug fixed here: pair table is 3136 B = 196 float4s — stage ALL of it
// (tid<98 left pairs 392..783 uninitialized -> NaN).
__global__ __launch_bounds__(256) void afm_main(
    const float* __restrict__ x, const float* __restrict__ bvec,
    const float* __restrict__ hvec, const unsigned char* __restrict__ ws,
    float* __restrict__ out) {
  // LDS: 5760 + 3136 + 3136 + 3136 + 48 = 15.2 KB
  __shared__ __align__(16) _Float16 xh[40 * 72];  // row stride 144 B
  __shared__ __align__(16) unsigned int tblu[784];
  __shared__ float scs[784];
  __shared__ float s2s[784];
  __shared__ float red[12];

  const int tid = threadIdx.x;
  const int b = blockIdx.x;
  const int lane = tid & 63;
  const int wid = tid >> 6;      // 0..3
  const int m = lane & 15, kg = lane >> 4;

  // ---- issue x[b] loads first (longest latency path) ----
  const float4* xg = (const float4*)(x + b * 2560);
  float4 v0 = xg[tid];
  float4 v1 = xg[256 + tid];
  float4 v2;
  if (tid < 128) v2 = xg[512 + tid];

  // ---- stage pair table -> LDS (196 float4s = 784 uints) ----
  {
    const float4* tg = (const float4*)(ws + 10240);
    float4* ts = (float4*)tblu;
    if (tid < 196) ts[tid] = tg[tid];
  }

  // ---- W/pvec fragments + bias/h float4s (L2-hot) ----
  const half8v* wfg = (const half8v*)ws;
  half8v wf[2][4];
#pragma unroll
  for (int ks = 0; ks < 2; ++ks)
#pragma unroll
    for (int nt = 0; nt < 4; ++nt) wf[ks][nt] = wfg[(ks * 4 + nt) * 64 + lane];
  const half8v* pfg = (const half8v*)(ws + 8192);
  half8v pf[2] = {pfg[lane], pfg[64 + lane]};
  f32x4 buv[4], huv[4];
#pragma unroll
  for (int nt = 0; nt < 4; ++nt) {
    buv[nt] = *(const f32x4*)&bvec[nt * 16 + kg * 4];   // bias for rows u=nt*16+kg*4+r
    huv[nt] = *(const f32x4*)&hvec[nt * 16 + kg * 4];
  }

  // ---- stage x -> LDS fp16 (row stride 72 halves) ----
  {
    int f = tid >> 4, e4 = tid & 15;
    half2v* dst = (half2v*)&xh[f * 72 + e4 * 4];
    dst[0] = __builtin_bit_cast(half2v, __builtin_amdgcn_cvt_pkrtz(v0.x, v0.y));
    dst[1] = __builtin_bit_cast(half2v, __builtin_amdgcn_cvt_pkrtz(v0.z, v0.w));
  }
  {
    int g = 256 + tid;
    int f = g >> 4, e4 = g & 15;
    half2v* dst = (half2v*)&xh[f * 72 + e4 * 4];
    dst[0] = __builtin_bit_cast(half2v, __builtin_amdgcn_cvt_pkrtz(v1.x, v1.y));
    dst[1] = __builtin_bit_cast(half2v, __builtin_amdgcn_cvt_pkrtz(v1.z, v1.w));
  }
  if (tid < 128) {
    int g = 512 + tid;
    int f = g >> 4, e4 = g & 15;
    half2v* dst = (half2v*)&xh[f * 72 + e4 * 4];
    dst[0] = __builtin_bit_cast(half2v, __builtin_amdgcn_cvt_pkrtz(v2.x, v2.y));
    dst[1] = __builtin_bit_cast(half2v, __builtin_amdgcn_cvt_pkrtz(v2.z, v2.w));
  }
  __syncthreads();

  // ---- phase A: 13 tiles/wave, 2-deep software pipeline, fully unrolled ----
  const int eoff = kg * 8;
  const f32x4 zv = (f32x4){0.f, 0.f, 0.f, 0.f};
  unsigned int off[2];
  half8v xia[2][2], xja[2][2];
  off[0] = tblu[16 * wid + m];            // tile i=0 (t=wid<=3)
  ISSUE_READS(0, off[0]);
  off[1] = tblu[16 * (wid + 4) + m];      // tile i=1 (t<=7)
#pragma unroll
  for (int i = 0; i < 13; ++i) {
    const int cur = i & 1, nxt = cur ^ 1;
    if (i < 12) ISSUE_READS(nxt, off[nxt]);
    if (i < 11) {
      int tn = wid + 4 * (i + 2);
      tn = tn > 48 ? 48 : tn;
      off[cur] = tblu[16 * tn + m];
    }
    half8v a0 = xia[cur][0] * xja[cur][0];   // ip^T frag, e = kg*8+j
    half8v a1 = xia[cur][1] * xja[cur][1];   // ip^T frag, e = 32+kg*8+j
    // V^T: D[u=nt*16+kg*4+r][pair=m]; bias folded via C operand (no movs)
    f32x4 acc[4];
#pragma unroll
    for (int nt = 0; nt < 4; ++nt) {
      acc[nt] = __builtin_amdgcn_mfma_f32_16x16x32_f16(wf[0][nt], a0, buv[nt], 0, 0, 0);
      acc[nt] = __builtin_amdgcn_mfma_f32_16x16x32_f16(wf[1][nt], a1, acc[nt], 0, 0, 0);
    }
    f32x4 accp = __builtin_amdgcn_mfma_f32_16x16x32_f16(pf[0], a0, zv, 0, 0, 0);
    accp = __builtin_amdgcn_mfma_f32_16x16x32_f16(pf[1], a1, accp, 0, 0, 0);

    // lane-local relu-dot over this lane's 16 u-values (4 independent chains)
    float sp0 = fmaxf(acc[0][0], 0.f) * huv[0][0];
    float sp1 = fmaxf(acc[1][0], 0.f) * huv[1][0];
    float sp2 = fmaxf(acc[2][0], 0.f) * huv[2][0];
    float sp3 = fmaxf(acc[3][0], 0.f) * huv[3][0];
#pragma unroll
    for (int r = 1; r < 4; ++r) {
      sp0 = fmaf(fmaxf(acc[0][r], 0.f), huv[0][r], sp0);
      sp1 = fmaf(fmaxf(acc[1][r], 0.f), huv[1][r], sp1);
      sp2 = fmaf(fmaxf(acc[2][r], 0.f), huv[2][r], sp2);
      sp3 = fmaf(fmaxf(acc[3][r], 0.f), huv[3][r], sp3);
    }
    float s = (sp0 + sp1) + (sp2 + sp3);
    // reduce over the 4 kg groups (lanes m, m+16, m+32, m+48)
    s += __shfl_xor(s, 16);
    s += __shfl_xor(s, 32);

    int tt = wid + 4 * i;
    tt = tt > 48 ? 48 : tt;
    if (kg == 0) {                       // 16 lanes, coalesced 16-float rows
      scs[16 * tt + m] = s;
      s2s[16 * tt + m] = accp[0];        // D[0][pair=m] lives in reg 0 of kg==0
    }
  }
  __syncthreads();

  // ---- phase B: softmax over 780 + weighted sum of s2 (256 threads) ----
  float sv[4];
  float mx = -1e30f;
#pragma unroll
  for (int k2 = 0; k2 < 4; ++k2) {
    int p = tid + k2 * 256;
    if (p < 780) {
      sv[k2] = scs[p];
      mx = fmaxf(mx, sv[k2]);
    } else {
      sv[k2] = -1e30f;
    }
  }
#pragma unroll
  for (int o = 32; o; o >>= 1) mx = fmaxf(mx, __shfl_xor(mx, o));
  if (lane == 0) red[wid] = mx;
  __syncthreads();
  mx = fmaxf(fmaxf(red[0], red[1]), fmaxf(red[2], red[3]));
  float num = 0.f, den = 0.f;
#pragma unroll
  for (int k2 = 0; k2 < 4; ++k2) {
    int p = tid + k2 * 256;
    if (p < 780) {
      float e = __expf(sv[k2] - mx);
      num += e * s2s[p];
      den += e;
    }
  }
#pragma unroll
  for (int o = 32; o; o >>= 1) {
    num += __shfl_xor(num, o);
    den += __shfl_xor(den, o);
  }
  if (lane == 0) { red[4 + wid] = num; red[8 + wid] = den; }
  __syncthreads();
  if (tid == 0)
    out[b] = (red[4] + red[5] + red[6] + red[7]) /
             (red[8] + red[9] + red[10] + red[11]);
}

extern "C" void kernel_launch(void* const* d_in, const int* in_sizes, int n_in,
                              void* d_out, int out_size, void* d_ws, size_t ws_size,
                              hipStream_t stream) {
  const float* x    = (const float*)d_in[0];  // [4096,40,64]
  const float* W    = (const float*)d_in[1];  // [64,64]
  const float* bvec = (const float*)d_in[2];  // [64]
  const float* hvec = (const float*)d_in[3];  // [64,1]
  const float* pvec = (const float*)d_in[4];  // [64,1]
  float* out = (float*)d_out;                 // [4096,1]
  unsigned char* ws = (unsigned char*)d_ws;   // needs 13.4 KB

  hipLaunchKernelGGL(afm_prep, dim3(1), dim3(256), 0, stream, W, pvec, ws);
  hipLaunchKernelGGL(afm_main, dim3(4096), dim3(256), 0, stream,
                     x, bvec, hvec, ws, out);
}